// Round 5
// baseline (384.657 us; speedup 1.0000x reference)
//
#include <hip/hip_runtime.h>
#include <math.h>

#define NN 512
#define H 256
#define NHEAD 8
#define DK 32
#define NLAYER 6
#define QSCALE 0.17677669529663687f

typedef __attribute__((ext_vector_type(8))) short bf16x8;
typedef __attribute__((ext_vector_type(4))) short bf16x4;
typedef __attribute__((ext_vector_type(4))) float f32x4;

__device__ __forceinline__ short f2bf(float f) {
  union { float f; unsigned u; } v; v.f = f;
  unsigned r = (v.u + 0x7FFFu + ((v.u >> 16) & 1u)) >> 16;
  return (short)r;
}
__device__ __forceinline__ float bf2f(short s) {
  union { unsigned u; float f; } v; v.u = ((unsigned)(unsigned short)s) << 16;
  return v.f;
}

__device__ __forceinline__ float blk_sum(float v) {
  __shared__ float sb[4];
  #pragma unroll
  for (int o = 32; o; o >>= 1) v += __shfl_down(v, o, 64);
  if ((threadIdx.x & 63) == 0) sb[threadIdx.x >> 6] = v;
  __syncthreads();
  v = sb[0] + sb[1] + sb[2] + sb[3];
  __syncthreads();
  return v;
}

// ---------- per-table-row projections (rows 0..31 ee, 32..159 ed) ----------
__global__ __launch_bounds__(256) void proj_kernel(
    const float* __restrict__ edge_emb, const float* __restrict__ edge_dist_emb,
    const float* __restrict__ W_ee, const float* __restrict__ W_ed,
    float* __restrict__ eeP, float* __restrict__ edP) {
  int r = blockIdx.x;
  const float* table; const float* W; float* out; int row;
  if (r < 32) { table = edge_emb;      W = W_ee; out = eeP; row = r; }
  else        { table = edge_dist_emb; W = W_ed; out = edP; row = r - 32; }
  int t = threadIdx.x;
  float val = table[row * H + t];
  float ss = blk_sum(val * val);
  float n = sqrtf(ss);
  float sc = (n > 1.f) ? 1.f / (n + 1e-7f) : 1.f;
  float v = val * sc;
  #pragma unroll
  for (int hh = 0; hh < NHEAD; hh++) {
    float p = blk_sum(v * W[t * NHEAD + hh]);
    if (t == 0) out[row * NHEAD + hh] = p;
  }
}

// ---------- build attn_bias [NH][N][N] bf16 ----------
__global__ __launch_bounds__(256) void bias_kernel(
    const int* __restrict__ ee, const int* __restrict__ ed,
    const float* __restrict__ eeP, const float* __restrict__ edP,
    const float* __restrict__ b_ee, const float* __restrict__ b_ed,
    short* __restrict__ bias) {
  __shared__ float seeP[32 * 8];
  __shared__ float sedP[128 * 8];
  __shared__ float sbe[8], sbd[8];
  int t = threadIdx.x;
  seeP[t] = eeP[t];
  #pragma unroll
  for (int i = 0; i < 4; i++) sedP[t + i * 256] = edP[t + i * 256];
  if (t < 8) { sbe[t] = b_ee[t]; sbd[t] = b_ed[t]; }
  __syncthreads();
  int idx = blockIdx.x * 256 + t;
  int e0 = ee[idx * 2], e1 = ee[idx * 2 + 1];
  int d = ed[idx];
  #pragma unroll
  for (int hh = 0; hh < NHEAD; hh++) {
    bias[hh * (NN * NN) + idx] = f2bf(
        0.5f * (seeP[e0 * 8 + hh] + seeP[e1 * 8 + hh]) + sbe[hh]
        + sedP[d * 8 + hh] + sbd[hh]);
  }
}

// ---------- transpose+cast all weights to bf16 WT[n][k] ----------
// blocks 0..2303: per-layer {Wq(scaled),Wk,Wv -> Aqkv | Wo,W1,W2}; 2304..2367: W_feat
__global__ __launch_bounds__(256) void wcast_kernel(
    const float* __restrict__ Wq, const float* __restrict__ Wk,
    const float* __restrict__ Wv, const float* __restrict__ Wo,
    const float* __restrict__ W1, const float* __restrict__ W2,
    const float* __restrict__ Wf,
    short* __restrict__ Aqkv, short* __restrict__ AoT,
    short* __restrict__ A1T, short* __restrict__ A2T, short* __restrict__ WfT) {
  __shared__ float tile[32][33];
  int b = blockIdx.x;
  const float* src; short* dst; float scl = 1.f;
  int t;
  if (b < 2304) {
    int l = b / 384; int rr = b % 384; int mat = rr / 64; t = rr % 64;
    if      (mat == 0) { src = Wq + l * 65536; dst = Aqkv + l * 196608; scl = QSCALE; }
    else if (mat == 1) { src = Wk + l * 65536; dst = Aqkv + l * 196608 + 65536; }
    else if (mat == 2) { src = Wv + l * 65536; dst = Aqkv + l * 196608 + 131072; }
    else if (mat == 3) { src = Wo + l * 65536; dst = AoT + l * 65536; }
    else if (mat == 4) { src = W1 + l * 65536; dst = A1T + l * 65536; }
    else               { src = W2 + l * 65536; dst = A2T + l * 65536; }
  } else {
    src = Wf; dst = WfT; t = b - 2304;
  }
  int tr = t >> 3, tc = t & 7;
  int tid = threadIdx.x;
  int kl = tid >> 3, nl4 = (tid & 7) * 4;
  float4 v = *(const float4*)(src + (tr * 32 + kl) * 256 + tc * 32 + nl4);
  tile[kl][nl4 + 0] = v.x; tile[kl][nl4 + 1] = v.y;
  tile[kl][nl4 + 2] = v.z; tile[kl][nl4 + 3] = v.w;
  __syncthreads();
  int nl = tid >> 3, kl4 = (tid & 7) * 4;
  bf16x4 o;
  #pragma unroll
  for (int i = 0; i < 4; i++) o[i] = f2bf(tile[kl4 + i][nl] * scl);
  *(bf16x4*)(dst + (tc * 32 + nl) * 256 + tr * 32 + kl4) = o;
}

// ---------- row-local layernorm over 16 rows in LDS ----------
__device__ __forceinline__ void ln_rows(const float* __restrict__ hb,
    const float* __restrict__ s, const float* __restrict__ b,
    short* __restrict__ yb, int tid) {
  int row = tid >> 4, j = tid & 15;
  const float* rp = hb + row * 256 + j * 16;
  float loc[16]; float sum = 0.f;
  #pragma unroll
  for (int i = 0; i < 16; i++) { loc[i] = rp[i]; sum += loc[i]; }
  #pragma unroll
  for (int o = 8; o; o >>= 1) sum += __shfl_xor(sum, o, 16);
  float mean = sum * (1.f / 256.f);
  float var = 0.f;
  #pragma unroll
  for (int i = 0; i < 16; i++) { float d = loc[i] - mean; var += d * d; }
  #pragma unroll
  for (int o = 8; o; o >>= 1) var += __shfl_xor(var, o, 16);
  float inv = rsqrtf(var * (1.f / 256.f) + 1e-5f);
  #pragma unroll
  for (int i = 0; i < 16; i++)
    yb[row * 256 + j * 16 + i] =
        f2bf((loc[i] - mean) * inv * s[j * 16 + i] + b[j * 16 + i]);
}

// ---------- QKV GEMM from LDS-A, fused q/k/vT epilogue ----------
__device__ __forceinline__ void qkv_stage(
    const short* __restrict__ Abuf, const short* __restrict__ Aqkv,
    const float* __restrict__ bq, const float* __restrict__ bk,
    const float* __restrict__ bv,
    short* __restrict__ q_bf, short* __restrict__ k_bf, short* __restrict__ vT_bf,
    int m0, int w, int lr, int lk) {
  f32x4 acc[12] = {};
  int nb = w * 192;
  for (int k0 = 0; k0 < 256; k0 += 32) {
    bf16x8 af = *(const bf16x8*)(Abuf + lr * 256 + k0 + lk * 8);
    #pragma unroll
    for (int t = 0; t < 12; t++) {
      bf16x8 bfr = *(const bf16x8*)(Aqkv + (nb + t * 16 + lr) * 256 + k0 + lk * 8);
      acc[t] = __builtin_amdgcn_mfma_f32_16x16x32_bf16(af, bfr, acc[t], 0, 0, 0);
    }
  }
  #pragma unroll
  for (int t = 0; t < 12; t++) {
    int n = nb + t * 16 + lr;
    #pragma unroll
    for (int r = 0; r < 4; r++) {
      int gm = m0 + lk * 4 + r;
      float v = acc[t][r];
      if (n < 256) {
        q_bf[((n >> 5) * 512 + gm) * 32 + (n & 31)] = f2bf(v + bq[n] * QSCALE);
      } else if (n < 512) {
        int nn = n - 256;
        k_bf[((nn >> 5) * 512 + gm) * 32 + (nn & 31)] = f2bf(v + bk[nn]);
      } else {
        int nn = n - 512;
        vT_bf[nn * 512 + gm] = f2bf(v + bv[nn]);
      }
    }
  }
}

// ---------- feat: h = x@Wf + b ; LN1 ; QKV (layer 0) ----------
__global__ __launch_bounds__(256) void feat_kernel(
    const float* __restrict__ x, const short* __restrict__ WfT,
    const float* __restrict__ b_feat, float* __restrict__ h,
    const float* __restrict__ ln1_s, const float* __restrict__ ln1_b,
    const short* __restrict__ Aqkv, const float* __restrict__ bq,
    const float* __restrict__ bk, const float* __restrict__ bv,
    short* __restrict__ q_bf, short* __restrict__ k_bf, short* __restrict__ vT_bf) {
  __shared__ short Abuf[16 * 256];
  __shared__ float hbuf[16 * 256];
  int tid = threadIdx.x, w = tid >> 6, l = tid & 63, lr = l & 15, lk = l >> 4;
  int m0 = blockIdx.x * 16;
  {
    int row = tid >> 4, j = tid & 15;
    const float4* xp = (const float4*)(x + (m0 + row) * 256 + j * 16);
    #pragma unroll
    for (int q4 = 0; q4 < 4; q4++) {
      float4 v = xp[q4];
      Abuf[row * 256 + j * 16 + q4 * 4 + 0] = f2bf(v.x);
      Abuf[row * 256 + j * 16 + q4 * 4 + 1] = f2bf(v.y);
      Abuf[row * 256 + j * 16 + q4 * 4 + 2] = f2bf(v.z);
      Abuf[row * 256 + j * 16 + q4 * 4 + 3] = f2bf(v.w);
    }
  }
  __syncthreads();
  f32x4 acc[4] = {};
  int nb = w * 64;
  for (int k0 = 0; k0 < 256; k0 += 32) {
    bf16x8 af = *(const bf16x8*)(Abuf + lr * 256 + k0 + lk * 8);
    #pragma unroll
    for (int t = 0; t < 4; t++) {
      bf16x8 bfr = *(const bf16x8*)(WfT + (nb + t * 16 + lr) * 256 + k0 + lk * 8);
      acc[t] = __builtin_amdgcn_mfma_f32_16x16x32_bf16(af, bfr, acc[t], 0, 0, 0);
    }
  }
  #pragma unroll
  for (int t = 0; t < 4; t++) {
    int n = nb + t * 16 + lr;
    #pragma unroll
    for (int r = 0; r < 4; r++) {
      int m = lk * 4 + r;
      float v = acc[t][r] + b_feat[n];
      hbuf[m * 256 + n] = v;
      h[(m0 + m) * 256 + n] = v;
    }
  }
  __syncthreads();
  ln_rows(hbuf, ln1_s, ln1_b, Abuf, tid);
  __syncthreads();
  qkv_stage(Abuf, Aqkv, bq, bk, bv, q_bf, k_bf, vT_bf, m0, w, lr, lk);
}

// ---------- fused attention per (qtile 32 rows, head) ----------
#define SSTR 516
#define PSTR 520
__global__ __launch_bounds__(256) void attn_kernel(
    const short* __restrict__ qb, const short* __restrict__ kb,
    const short* __restrict__ vT, const short* __restrict__ bias,
    short* __restrict__ ob) {
  __shared__ float S[32 * SSTR];
  __shared__ short P[32 * PSTR];
  __shared__ short Kst[64 * 32];
  int h = blockIdx.y, m0 = blockIdx.x * 32;
  int tid = threadIdx.x, w = tid >> 6, l = tid & 63;

  const short* qrow = qb + (h * 512 + m0) * 32;
  bf16x8 aq0 = *(const bf16x8*)(qrow + (l & 15) * 32 + (l >> 4) * 8);
  bf16x8 aq1 = *(const bf16x8*)(qrow + (16 + (l & 15)) * 32 + (l >> 4) * 8);

  int snode = tid >> 2, sseg = tid & 3;
  for (int c = 0; c < 8; c++) {
    *(bf16x8*)(Kst + snode * 32 + sseg * 8) =
        *(const bf16x8*)(kb + (h * 512 + c * 64 + snode) * 32 + sseg * 8);
    __syncthreads();
    bf16x8 bk = *(const bf16x8*)(Kst + (w * 16 + (l & 15)) * 32 + (l >> 4) * 8);
    f32x4 s0 = {}, s1 = {};
    s0 = __builtin_amdgcn_mfma_f32_16x16x32_bf16(aq0, bk, s0, 0, 0, 0);
    s1 = __builtin_amdgcn_mfma_f32_16x16x32_bf16(aq1, bk, s1, 0, 0, 0);
    int node = c * 64 + w * 16 + (l & 15);
    #pragma unroll
    for (int r = 0; r < 4; r++) {
      int r0 = (l >> 4) * 4 + r;
      S[r0 * SSTR + node] = s0[r] + bf2f(bias[(h * 512 + m0 + r0) * 512 + node]);
      S[(16 + r0) * SSTR + node] =
          s1[r] + bf2f(bias[(h * 512 + m0 + 16 + r0) * 512 + node]);
    }
    __syncthreads();
  }

  {
    int r = tid >> 3, j = tid & 7;
    float* Srow = S + r * SSTR;
    float mx = -1e30f;
    #pragma unroll 8
    for (int t = 0; t < 64; t++) mx = fmaxf(mx, Srow[j + t * 8]);
    #pragma unroll
    for (int o = 4; o; o >>= 1) mx = fmaxf(mx, __shfl_xor(mx, o, 8));
    float sum = 0.f;
    #pragma unroll 8
    for (int t = 0; t < 64; t++) sum += __expf(Srow[j + t * 8] - mx);
    #pragma unroll
    for (int o = 4; o; o >>= 1) sum += __shfl_xor(sum, o, 8);
    float inv = 1.f / sum;
    #pragma unroll 8
    for (int t = 0; t < 64; t++)
      P[r * PSTR + j + t * 8] = f2bf(__expf(Srow[j + t * 8] - mx) * inv);
  }
  __syncthreads();

  int msub = (w >> 1) * 16, nsub = (w & 1) * 16;
  const short* vrow = vT + (h * 32 + nsub + (l & 15)) * 512;
  f32x4 oc = {};
  #pragma unroll
  for (int ch = 0; ch < 16; ch++) {
    bf16x8 ap = *(bf16x8*)(P + (msub + (l & 15)) * PSTR + ch * 32 + (l >> 4) * 8);
    bf16x8 bv = *(const bf16x8*)(vrow + ch * 32 + (l >> 4) * 8);
    oc = __builtin_amdgcn_mfma_f32_16x16x32_bf16(ap, bv, oc, 0, 0, 0);
  }
  #pragma unroll
  for (int r = 0; r < 4; r++)
    ob[(m0 + msub + (l >> 4) * 4 + r) * 256 + h * 32 + nsub + (l & 15)] = f2bf(oc[r]);
}

// ---------- tail: O-proj+resid, LN2, FFN1+gelu, FFN2+resid, LN1n, QKVn ----------
__global__ __launch_bounds__(256) void tail_kernel(
    const short* __restrict__ o_bf, float* __restrict__ h,
    const short* __restrict__ AoT, const float* __restrict__ bo,
    const float* __restrict__ ln2_s, const float* __restrict__ ln2_b,
    const short* __restrict__ A1T, const float* __restrict__ b1,
    const short* __restrict__ A2T, const float* __restrict__ b2,
    const float* __restrict__ ln1_s, const float* __restrict__ ln1_b,
    const short* __restrict__ Aqkv, const float* __restrict__ bq,
    const float* __restrict__ bk, const float* __restrict__ bv,
    short* __restrict__ q_bf, short* __restrict__ k_bf, short* __restrict__ vT_bf,
    int last) {
  __shared__ short Abuf[16 * 256];
  __shared__ short Gbuf[16 * 256];
  __shared__ float hbuf[16 * 256];
  int tid = threadIdx.x, w = tid >> 6, l = tid & 63, lr = l & 15, lk = l >> 4;
  int m0 = blockIdx.x * 16;
  {
    int row = tid >> 4, j = tid & 15;
    *(bf16x8*)(Abuf + row * 256 + j * 16) =
        *(const bf16x8*)(o_bf + (m0 + row) * 256 + j * 16);
    *(bf16x8*)(Abuf + row * 256 + j * 16 + 8) =
        *(const bf16x8*)(o_bf + (m0 + row) * 256 + j * 16 + 8);
  }
  __syncthreads();
  int nb = w * 64;
  // O-proj + residual -> hbuf
  {
    f32x4 acc[4] = {};
    for (int k0 = 0; k0 < 256; k0 += 32) {
      bf16x8 af = *(const bf16x8*)(Abuf + lr * 256 + k0 + lk * 8);
      #pragma unroll
      for (int t = 0; t < 4; t++) {
        bf16x8 bfr = *(const bf16x8*)(AoT + (nb + t * 16 + lr) * 256 + k0 + lk * 8);
        acc[t] = __builtin_amdgcn_mfma_f32_16x16x32_bf16(af, bfr, acc[t], 0, 0, 0);
      }
    }
    #pragma unroll
    for (int t = 0; t < 4; t++) {
      int n = nb + t * 16 + lr;
      #pragma unroll
      for (int r = 0; r < 4; r++) {
        int m = lk * 4 + r;
        hbuf[m * 256 + n] = h[(m0 + m) * 256 + n] + acc[t][r] + bo[n];
      }
    }
  }
  __syncthreads();
  ln_rows(hbuf, ln2_s, ln2_b, Abuf, tid);
  __syncthreads();
  // FFN1 + gelu -> Gbuf
  {
    f32x4 acc[4] = {};
    for (int k0 = 0; k0 < 256; k0 += 32) {
      bf16x8 af = *(const bf16x8*)(Abuf + lr * 256 + k0 + lk * 8);
      #pragma unroll
      for (int t = 0; t < 4; t++) {
        bf16x8 bfr = *(const bf16x8*)(A1T + (nb + t * 16 + lr) * 256 + k0 + lk * 8);
        acc[t] = __builtin_amdgcn_mfma_f32_16x16x32_bf16(af, bfr, acc[t], 0, 0, 0);
      }
    }
    #pragma unroll
    for (int t = 0; t < 4; t++) {
      int n = nb + t * 16 + lr;
      #pragma unroll
      for (int r = 0; r < 4; r++) {
        int m = lk * 4 + r;
        float val = acc[t][r] + b1[n];
        Gbuf[m * 256 + n] =
            f2bf(0.5f * val * (1.f + erff(val * 0.70710678118654752f)));
      }
    }
  }
  __syncthreads();
  // FFN2 + residual -> h global (+hbuf)
  {
    f32x4 acc[4] = {};
    for (int k0 = 0; k0 < 256; k0 += 32) {
      bf16x8 af = *(const bf16x8*)(Gbuf + lr * 256 + k0 + lk * 8);
      #pragma unroll
      for (int t = 0; t < 4; t++) {
        bf16x8 bfr = *(const bf16x8*)(A2T + (nb + t * 16 + lr) * 256 + k0 + lk * 8);
        acc[t] = __builtin_amdgcn_mfma_f32_16x16x32_bf16(af, bfr, acc[t], 0, 0, 0);
      }
    }
    #pragma unroll
    for (int t = 0; t < 4; t++) {
      int n = nb + t * 16 + lr;
      #pragma unroll
      for (int r = 0; r < 4; r++) {
        int m = lk * 4 + r;
        float hv = hbuf[m * 256 + n] + acc[t][r] + b2[n];
        h[(m0 + m) * 256 + n] = hv;
        hbuf[m * 256 + n] = hv;
      }
    }
  }
  __syncthreads();
  if (!last) {
    ln_rows(hbuf, ln1_s, ln1_b, Abuf, tid);
    __syncthreads();
    qkv_stage(Abuf, Aqkv, bq, bk, bv, q_bf, k_bf, vT_bf, m0, w, lr, lk);
  }
}

extern "C" void kernel_launch(void* const* d_in, const int* in_sizes, int n_in,
                              void* d_out, int out_size, void* d_ws, size_t ws_size,
                              hipStream_t stream) {
  const float* x             = (const float*)d_in[0];
  const int*   edge_encodes  = (const int*)d_in[2];
  const int*   edge_dist_enc = (const int*)d_in[3];
  const float* W_feat = (const float*)d_in[7];
  const float* b_feat = (const float*)d_in[8];
  const float* edge_emb      = (const float*)d_in[9];
  const float* edge_dist_emb = (const float*)d_in[10];
  const float* W_ee = (const float*)d_in[11];
  const float* b_ee = (const float*)d_in[12];
  const float* W_ed = (const float*)d_in[13];
  const float* b_ed = (const float*)d_in[14];
  const float* ln1_s = (const float*)d_in[15];
  const float* ln1_b = (const float*)d_in[16];
  const float* Wq = (const float*)d_in[17];
  const float* bq = (const float*)d_in[18];
  const float* Wk = (const float*)d_in[19];
  const float* bk = (const float*)d_in[20];
  const float* Wv = (const float*)d_in[21];
  const float* bv = (const float*)d_in[22];
  const float* Wo = (const float*)d_in[23];
  const float* bo = (const float*)d_in[24];
  const float* ln2_s = (const float*)d_in[25];
  const float* ln2_b = (const float*)d_in[26];
  const float* W1 = (const float*)d_in[27];
  const float* b1 = (const float*)d_in[28];
  const float* W2 = (const float*)d_in[29];
  const float* b2 = (const float*)d_in[30];

  float* h = (float*)d_out;
  char* base = (char*)d_ws;
  short* bias_bf = (short*)base;                      // 4 MB
  short* Aqkv = (short*)(base + 4194304);             // 6*196608*2
  short* AoT  = (short*)(base + 6553600);
  short* A1T  = (short*)(base + 7340032);
  short* A2T  = (short*)(base + 8126464);
  short* WfT  = (short*)(base + 8912896);
  short* q_bf = (short*)(base + 9043968);
  short* k_bf = (short*)(base + 9306112);
  short* vT_bf= (short*)(base + 9568256);
  short* o_bf = (short*)(base + 9830400);
  float* eeP  = (float*)(base + 10092544);
  float* edP  = (float*)(base + 10093568);

  wcast_kernel<<<2368, 256, 0, stream>>>(Wq, Wk, Wv, Wo, W1, W2, W_feat,
                                         Aqkv, AoT, A1T, A2T, WfT);
  proj_kernel<<<160, 256, 0, stream>>>(edge_emb, edge_dist_emb, W_ee, W_ed, eeP, edP);
  bias_kernel<<<1024, 256, 0, stream>>>(edge_encodes, edge_dist_enc, eeP, edP,
                                        b_ee, b_ed, bias_bf);

  feat_kernel<<<32, 256, 0, stream>>>(x, WfT, b_feat, h,
                                      ln1_s, ln1_b, Aqkv, bq, bk, bv,
                                      q_bf, k_bf, vT_bf);

  for (int l = 0; l < NLAYER; l++) {
    int ln = (l < NLAYER - 1) ? l + 1 : l;   // clamped (unused when last)
    attn_kernel<<<dim3(16, 8), 256, 0, stream>>>(q_bf, k_bf, vT_bf, bias_bf, o_bf);
    tail_kernel<<<32, 256, 0, stream>>>(
        o_bf, h,
        AoT + l * 65536, bo + l * H,
        ln2_s + l * H, ln2_b + l * H,
        A1T + l * 65536, b1 + l * H,
        A2T + l * 65536, b2 + l * H,
        ln1_s + ln * H, ln1_b + ln * H,
        Aqkv + ln * 196608, bq + ln * H, bk + ln * H, bv + ln * H,
        q_bf, k_bf, vT_bf, l == NLAYER - 1);
  }
}

// Round 6
// 349.843 us; speedup vs baseline: 1.0995x; 1.0995x over previous
//
#include <hip/hip_runtime.h>
#include <math.h>

#define NN 512
#define H 256
#define NHEAD 8
#define DK 32
#define NLAYER 6
#define QSCALE 0.17677669529663687f
#define SSTR 520   // padded S/P row stride (shorts)

typedef __attribute__((ext_vector_type(8))) short bf16x8;
typedef __attribute__((ext_vector_type(4))) short bf16x4;
typedef __attribute__((ext_vector_type(4))) float f32x4;

__device__ __forceinline__ short f2bf(float f) {
  union { float f; unsigned u; } v; v.f = f;
  unsigned r = (v.u + 0x7FFFu + ((v.u >> 16) & 1u)) >> 16;
  return (short)r;
}
__device__ __forceinline__ float bf2f(short s) {
  union { unsigned u; float f; } v; v.u = ((unsigned)(unsigned short)s) << 16;
  return v.f;
}

__device__ __forceinline__ float blk_sum(float v) {
  __shared__ float sb[4];
  #pragma unroll
  for (int o = 32; o; o >>= 1) v += __shfl_down(v, o, 64);
  if ((threadIdx.x & 63) == 0) sb[threadIdx.x >> 6] = v;
  __syncthreads();
  v = sb[0] + sb[1] + sb[2] + sb[3];
  __syncthreads();
  return v;
}

// ---------- per-table-row projections (rows 0..31 ee, 32..159 ed) ----------
__global__ __launch_bounds__(256) void proj_kernel(
    const float* __restrict__ edge_emb, const float* __restrict__ edge_dist_emb,
    const float* __restrict__ W_ee, const float* __restrict__ W_ed,
    float* __restrict__ eeP, float* __restrict__ edP) {
  int r = blockIdx.x;
  const float* table; const float* W; float* out; int row;
  if (r < 32) { table = edge_emb;      W = W_ee; out = eeP; row = r; }
  else        { table = edge_dist_emb; W = W_ed; out = edP; row = r - 32; }
  int t = threadIdx.x;
  float val = table[row * H + t];
  float ss = blk_sum(val * val);
  float n = sqrtf(ss);
  float sc = (n > 1.f) ? 1.f / (n + 1e-7f) : 1.f;
  float v = val * sc;
  #pragma unroll
  for (int hh = 0; hh < NHEAD; hh++) {
    float p = blk_sum(v * W[t * NHEAD + hh]);
    if (t == 0) out[row * NHEAD + hh] = p;
  }
}

// ---------- build attn_bias [NH][N][N] bf16 ----------
__global__ __launch_bounds__(256) void bias_kernel(
    const int* __restrict__ ee, const int* __restrict__ ed,
    const float* __restrict__ eeP, const float* __restrict__ edP,
    const float* __restrict__ b_ee, const float* __restrict__ b_ed,
    short* __restrict__ bias) {
  __shared__ float seeP[32 * 8];
  __shared__ float sedP[128 * 8];
  __shared__ float sbe[8], sbd[8];
  int t = threadIdx.x;
  seeP[t] = eeP[t];
  #pragma unroll
  for (int i = 0; i < 4; i++) sedP[t + i * 256] = edP[t + i * 256];
  if (t < 8) { sbe[t] = b_ee[t]; sbd[t] = b_ed[t]; }
  __syncthreads();
  int idx = blockIdx.x * 256 + t;
  int e0 = ee[idx * 2], e1 = ee[idx * 2 + 1];
  int d = ed[idx];
  #pragma unroll
  for (int hh = 0; hh < NHEAD; hh++) {
    bias[hh * (NN * NN) + idx] = f2bf(
        0.5f * (seeP[e0 * 8 + hh] + seeP[e1 * 8 + hh]) + sbe[hh]
        + sedP[d * 8 + hh] + sbd[hh]);
  }
}

// ---------- transpose+cast all weights to bf16 WT[n][k] ----------
__global__ __launch_bounds__(256) void wcast_kernel(
    const float* __restrict__ Wq, const float* __restrict__ Wk,
    const float* __restrict__ Wv, const float* __restrict__ Wo,
    const float* __restrict__ W1, const float* __restrict__ W2,
    const float* __restrict__ Wf,
    short* __restrict__ Aqkv, short* __restrict__ AoT,
    short* __restrict__ A1T, short* __restrict__ A2T, short* __restrict__ WfT) {
  __shared__ float tile[32][33];
  int b = blockIdx.x;
  const float* src; short* dst; float scl = 1.f;
  int t;
  if (b < 2304) {
    int l = b / 384; int rr = b % 384; int mat = rr / 64; t = rr % 64;
    if      (mat == 0) { src = Wq + l * 65536; dst = Aqkv + l * 196608; scl = QSCALE; }
    else if (mat == 1) { src = Wk + l * 65536; dst = Aqkv + l * 196608 + 65536; }
    else if (mat == 2) { src = Wv + l * 65536; dst = Aqkv + l * 196608 + 131072; }
    else if (mat == 3) { src = Wo + l * 65536; dst = AoT + l * 65536; }
    else if (mat == 4) { src = W1 + l * 65536; dst = A1T + l * 65536; }
    else               { src = W2 + l * 65536; dst = A2T + l * 65536; }
  } else {
    src = Wf; dst = WfT; t = b - 2304;
  }
  int tr = t >> 3, tc = t & 7;
  int tid = threadIdx.x;
  int kl = tid >> 3, nl4 = (tid & 7) * 4;
  float4 v = *(const float4*)(src + (tr * 32 + kl) * 256 + tc * 32 + nl4);
  tile[kl][nl4 + 0] = v.x; tile[kl][nl4 + 1] = v.y;
  tile[kl][nl4 + 2] = v.z; tile[kl][nl4 + 3] = v.w;
  __syncthreads();
  int nl = tid >> 3, kl4 = (tid & 7) * 4;
  bf16x4 o;
  #pragma unroll
  for (int i = 0; i < 4; i++) o[i] = f2bf(tile[kl4 + i][nl] * scl);
  *(bf16x4*)(dst + (tc * 32 + nl) * 256 + tr * 32 + kl4) = o;
}

// ---------- wave-per-row layernorm (16 waves, 16 rows) ----------
__device__ __forceinline__ void ln_rows16(const float* __restrict__ hb,
    const float* __restrict__ s, const float* __restrict__ b,
    short* __restrict__ yb, int w, int l) {
  const float* rp = hb + w * 256 + l * 4;
  float4 v = *(const float4*)rp;
  float sum = v.x + v.y + v.z + v.w;
  #pragma unroll
  for (int o = 32; o; o >>= 1) sum += __shfl_xor(sum, o);
  float mean = sum * (1.f / 256.f);
  float dx = v.x - mean, dy = v.y - mean, dz = v.z - mean, dw = v.w - mean;
  float var = dx * dx + dy * dy + dz * dz + dw * dw;
  #pragma unroll
  for (int o = 32; o; o >>= 1) var += __shfl_xor(var, o);
  float inv = rsqrtf(var * (1.f / 256.f) + 1e-5f);
  const float4 sv = *(const float4*)(s + l * 4);
  const float4 bv = *(const float4*)(b + l * 4);
  bf16x4 o4;
  o4[0] = f2bf(dx * inv * sv.x + bv.x);
  o4[1] = f2bf(dy * inv * sv.y + bv.y);
  o4[2] = f2bf(dz * inv * sv.z + bv.z);
  o4[3] = f2bf(dw * inv * sv.w + bv.w);
  *(bf16x4*)(yb + w * 256 + l * 4) = o4;
}

// ---------- QKV from Abuf (16 waves, wave w -> cols w*48..+47) ----------
__device__ __forceinline__ void qkv_stage16(
    const short* __restrict__ Abuf, const short* __restrict__ Aqkv,
    const float* __restrict__ bq, const float* __restrict__ bk,
    const float* __restrict__ bv,
    short* __restrict__ q_bf, short* __restrict__ k_bf, short* __restrict__ vT_bf,
    int m0, int w, int l) {
  int lr = l & 15, lk = l >> 4;
  f32x4 acc[3] = {};
  int nb = w * 48;
  for (int k0 = 0; k0 < 256; k0 += 32) {
    bf16x8 af = *(const bf16x8*)(Abuf + lr * 256 + k0 + lk * 8);
    #pragma unroll
    for (int t = 0; t < 3; t++) {
      bf16x8 bfr = *(const bf16x8*)(Aqkv + (nb + t * 16 + lr) * 256 + k0 + lk * 8);
      acc[t] = __builtin_amdgcn_mfma_f32_16x16x32_bf16(af, bfr, acc[t], 0, 0, 0);
    }
  }
  #pragma unroll
  for (int t = 0; t < 3; t++) {
    int n = nb + t * 16 + lr;
    #pragma unroll
    for (int r = 0; r < 4; r++) {
      int gm = m0 + lk * 4 + r;
      float v = acc[t][r];
      if (n < 256) {
        q_bf[((n >> 5) * 512 + gm) * 32 + (n & 31)] = f2bf(v + bq[n] * QSCALE);
      } else if (n < 512) {
        int nn = n - 256;
        k_bf[((nn >> 5) * 512 + gm) * 32 + (nn & 31)] = f2bf(v + bk[nn]);
      } else {
        int nn = n - 512;
        vT_bf[nn * 512 + gm] = f2bf(v + bv[nn]);
      }
    }
  }
}

// ---------- feat: h = x@Wf + b ; LN1 ; QKV layer0 ----------
__global__ __launch_bounds__(1024, 4) void feat_kernel(
    const float* __restrict__ x, const short* __restrict__ WfT,
    const float* __restrict__ b_feat, float* __restrict__ h,
    const float* __restrict__ ln1_s, const float* __restrict__ ln1_b,
    const short* __restrict__ Aqkv, const float* __restrict__ bq,
    const float* __restrict__ bk, const float* __restrict__ bv,
    short* __restrict__ q_bf, short* __restrict__ k_bf, short* __restrict__ vT_bf) {
  __shared__ __align__(16) short Abuf[16 * 256];
  __shared__ __align__(16) float hbuf[16 * 256];
  int tid = threadIdx.x, w = tid >> 6, l = tid & 63;
  int lr = l & 15, lk = l >> 4;
  int m0 = blockIdx.x * 16;
  {
    float4 v = *(const float4*)(x + (m0 + w) * 256 + l * 4);
    bf16x4 o4; o4[0] = f2bf(v.x); o4[1] = f2bf(v.y); o4[2] = f2bf(v.z); o4[3] = f2bf(v.w);
    *(bf16x4*)(Abuf + w * 256 + l * 4) = o4;
  }
  __syncthreads();
  {
    f32x4 acc = {};
    int nb = w * 16;
    for (int k0 = 0; k0 < 256; k0 += 32) {
      bf16x8 af = *(const bf16x8*)(Abuf + lr * 256 + k0 + lk * 8);
      bf16x8 bfr = *(const bf16x8*)(WfT + (nb + lr) * 256 + k0 + lk * 8);
      acc = __builtin_amdgcn_mfma_f32_16x16x32_bf16(af, bfr, acc, 0, 0, 0);
    }
    int n = nb + lr;
    #pragma unroll
    for (int r = 0; r < 4; r++) {
      int m = lk * 4 + r;
      float v = acc[r] + b_feat[n];
      hbuf[m * 256 + n] = v;
      h[(m0 + m) * 256 + n] = v;
    }
  }
  __syncthreads();
  ln_rows16(hbuf, ln1_s, ln1_b, Abuf, w, l);
  __syncthreads();
  qkv_stage16(Abuf, Aqkv, bq, bk, bv, q_bf, k_bf, vT_bf, m0, w, l);
}

// ---------- whole layer: attn + O-proj + LN2 + FFN + LN1n + QKVn ----------
__global__ __launch_bounds__(1024, 4) void layer_kernel(
    const short* __restrict__ qb, const short* __restrict__ kb,
    const short* __restrict__ vT, const short* __restrict__ bias,
    float* __restrict__ h,
    const short* __restrict__ AoT, const float* __restrict__ bo,
    const float* __restrict__ ln2_s, const float* __restrict__ ln2_b,
    const short* __restrict__ A1T, const float* __restrict__ b1,
    const short* __restrict__ A2T, const float* __restrict__ b2,
    const float* __restrict__ ln1_s, const float* __restrict__ ln1_b,
    const short* __restrict__ Aqkv, const float* __restrict__ bq,
    const float* __restrict__ bk, const float* __restrict__ bv,
    short* __restrict__ q_out, short* __restrict__ k_out, short* __restrict__ vT_out,
    int last) {
  __shared__ __align__(16) short SP[NHEAD * 16 * SSTR];   // 133120 B, S then P
  __shared__ __align__(16) float hbuf[16 * 256];          // 16384 B
  __shared__ __align__(16) short Abuf[16 * 256];          // 8192 B
  short* Gbuf = SP;                                       // aliased after PV

  int tid = threadIdx.x, w = tid >> 6, l = tid & 63;
  int lr = l & 15, lk = l >> 4;
  int m0 = blockIdx.x * 16;

  // ---- QK^T + bias -> SP (wave = head hq, node-half cq) ----
  {
    int hq = w >> 1, cq = w & 1;
    bf16x8 aq = *(const bf16x8*)(qb + (hq * 512 + m0 + lr) * 32 + lk * 8);
    #pragma unroll 4
    for (int j = 0; j < 16; j++) {
      int node0 = cq * 256 + j * 16;
      bf16x8 bk8 = *(const bf16x8*)(kb + (hq * 512 + node0 + lr) * 32 + lk * 8);
      f32x4 s = {};
      s = __builtin_amdgcn_mfma_f32_16x16x32_bf16(aq, bk8, s, 0, 0, 0);
      int gnode = node0 + lr;
      #pragma unroll
      for (int r = 0; r < 4; r++) {
        int row = lk * 4 + r;
        float logit = s[r] + bf2f(bias[(hq * 512 + m0 + row) * 512 + gnode]);
        SP[(hq * 16 + row) * SSTR + gnode] = f2bf(logit);
      }
    }
  }
  __syncthreads();

  // ---- softmax: 128 rows (8h x 16r), 8 threads/row ----
  {
    int rr = tid >> 3, j = tid & 7;
    short* Srow = SP + rr * SSTR;
    float mx = -1e30f;
    #pragma unroll 8
    for (int t = 0; t < 64; t++) mx = fmaxf(mx, bf2f(Srow[j + t * 8]));
    #pragma unroll
    for (int o = 4; o; o >>= 1) mx = fmaxf(mx, __shfl_xor(mx, o, 8));
    float sum = 0.f;
    #pragma unroll 8
    for (int t = 0; t < 64; t++) sum += __expf(bf2f(Srow[j + t * 8]) - mx);
    #pragma unroll
    for (int o = 4; o; o >>= 1) sum += __shfl_xor(sum, o, 8);
    float inv = 1.f / sum;
    #pragma unroll 8
    for (int t = 0; t < 64; t++)
      Srow[j + t * 8] = f2bf(__expf(bf2f(Srow[j + t * 8]) - mx) * inv);
  }
  __syncthreads();

  // ---- PV -> Abuf (wave = head hp, dk-half dh) ----
  {
    int hp = w >> 1, dh = w & 1;
    f32x4 oc = {};
    #pragma unroll 4
    for (int ch = 0; ch < 16; ch++) {
      bf16x8 ap = *(const bf16x8*)(SP + (hp * 16 + lr) * SSTR + ch * 32 + lk * 8);
      bf16x8 bv8 = *(const bf16x8*)(vT + (hp * 32 + dh * 16 + lr) * 512 + ch * 32 + lk * 8);
      oc = __builtin_amdgcn_mfma_f32_16x16x32_bf16(ap, bv8, oc, 0, 0, 0);
    }
    int col = hp * 32 + dh * 16 + lr;
    #pragma unroll
    for (int r = 0; r < 4; r++)
      Abuf[(lk * 4 + r) * 256 + col] = f2bf(oc[r]);
  }
  __syncthreads();

  // ---- O-proj + residual -> hbuf ----
  {
    f32x4 acc = {};
    int nb = w * 16;
    for (int k0 = 0; k0 < 256; k0 += 32) {
      bf16x8 af = *(const bf16x8*)(Abuf + lr * 256 + k0 + lk * 8);
      bf16x8 bfr = *(const bf16x8*)(AoT + (nb + lr) * 256 + k0 + lk * 8);
      acc = __builtin_amdgcn_mfma_f32_16x16x32_bf16(af, bfr, acc, 0, 0, 0);
    }
    int n = nb + lr;
    #pragma unroll
    for (int r = 0; r < 4; r++) {
      int m = lk * 4 + r;
      hbuf[m * 256 + n] = h[(m0 + m) * 256 + n] + acc[r] + bo[n];
    }
  }
  __syncthreads();
  ln_rows16(hbuf, ln2_s, ln2_b, Abuf, w, l);
  __syncthreads();

  // ---- FFN1 + gelu -> Gbuf (aliases SP) ----
  {
    f32x4 acc = {};
    int nb = w * 16;
    for (int k0 = 0; k0 < 256; k0 += 32) {
      bf16x8 af = *(const bf16x8*)(Abuf + lr * 256 + k0 + lk * 8);
      bf16x8 bfr = *(const bf16x8*)(A1T + (nb + lr) * 256 + k0 + lk * 8);
      acc = __builtin_amdgcn_mfma_f32_16x16x32_bf16(af, bfr, acc, 0, 0, 0);
    }
    int n = nb + lr;
    #pragma unroll
    for (int r = 0; r < 4; r++) {
      int m = lk * 4 + r;
      float val = acc[r] + b1[n];
      Gbuf[m * 256 + n] = f2bf(0.5f * val * (1.f + erff(val * 0.70710678118654752f)));
    }
  }
  __syncthreads();

  // ---- FFN2 + residual -> h global (+hbuf) ----
  {
    f32x4 acc = {};
    int nb = w * 16;
    for (int k0 = 0; k0 < 256; k0 += 32) {
      bf16x8 af = *(const bf16x8*)(Gbuf + lr * 256 + k0 + lk * 8);
      bf16x8 bfr = *(const bf16x8*)(A2T + (nb + lr) * 256 + k0 + lk * 8);
      acc = __builtin_amdgcn_mfma_f32_16x16x32_bf16(af, bfr, acc, 0, 0, 0);
    }
    int n = nb + lr;
    #pragma unroll
    for (int r = 0; r < 4; r++) {
      int m = lk * 4 + r;
      float hv = hbuf[m * 256 + n] + acc[r] + b2[n];
      h[(m0 + m) * 256 + n] = hv;
      hbuf[m * 256 + n] = hv;
    }
  }
  if (last) return;
  __syncthreads();
  ln_rows16(hbuf, ln1_s, ln1_b, Abuf, w, l);
  __syncthreads();
  qkv_stage16(Abuf, Aqkv, bq, bk, bv, q_out, k_out, vT_out, m0, w, l);
}

extern "C" void kernel_launch(void* const* d_in, const int* in_sizes, int n_in,
                              void* d_out, int out_size, void* d_ws, size_t ws_size,
                              hipStream_t stream) {
  const float* x             = (const float*)d_in[0];
  const int*   edge_encodes  = (const int*)d_in[2];
  const int*   edge_dist_enc = (const int*)d_in[3];
  const float* W_feat = (const float*)d_in[7];
  const float* b_feat = (const float*)d_in[8];
  const float* edge_emb      = (const float*)d_in[9];
  const float* edge_dist_emb = (const float*)d_in[10];
  const float* W_ee = (const float*)d_in[11];
  const float* b_ee = (const float*)d_in[12];
  const float* W_ed = (const float*)d_in[13];
  const float* b_ed = (const float*)d_in[14];
  const float* ln1_s = (const float*)d_in[15];
  const float* ln1_b = (const float*)d_in[16];
  const float* Wq = (const float*)d_in[17];
  const float* bq = (const float*)d_in[18];
  const float* Wk = (const float*)d_in[19];
  const float* bk = (const float*)d_in[20];
  const float* Wv = (const float*)d_in[21];
  const float* bv = (const float*)d_in[22];
  const float* Wo = (const float*)d_in[23];
  const float* bo = (const float*)d_in[24];
  const float* ln2_s = (const float*)d_in[25];
  const float* ln2_b = (const float*)d_in[26];
  const float* W1 = (const float*)d_in[27];
  const float* b1 = (const float*)d_in[28];
  const float* W2 = (const float*)d_in[29];
  const float* b2 = (const float*)d_in[30];

  float* h = (float*)d_out;
  char* base = (char*)d_ws;
  short* bias_bf = (short*)base;                      // 4 MB
  short* Aqkv = (short*)(base + 4194304);
  short* AoT  = (short*)(base + 6553600);
  short* A1T  = (short*)(base + 7340032);
  short* A2T  = (short*)(base + 8126464);
  short* WfT  = (short*)(base + 8912896);
  short* qkv0 = (short*)(base + 9043968);             // q,k,vT parity 0 (3*256KB)
  short* qkv1 = (short*)(base + 9830400);             // parity 1
  float* eeP  = (float*)(base + 10616832);
  float* edP  = (float*)(base + 10617856);

  wcast_kernel<<<2368, 256, 0, stream>>>(Wq, Wk, Wv, Wo, W1, W2, W_feat,
                                         Aqkv, AoT, A1T, A2T, WfT);
  proj_kernel<<<160, 256, 0, stream>>>(edge_emb, edge_dist_emb, W_ee, W_ed, eeP, edP);
  bias_kernel<<<1024, 256, 0, stream>>>(edge_encodes, edge_dist_enc, eeP, edP,
                                        b_ee, b_ed, bias_bf);

  short* q0 = qkv0, *k0 = qkv0 + 131072, *v0 = qkv0 + 262144;
  short* q1 = qkv1, *k1 = qkv1 + 131072, *v1 = qkv1 + 262144;

  feat_kernel<<<32, 1024, 0, stream>>>(x, WfT, b_feat, h,
                                       ln1_s, ln1_b, Aqkv, bq, bk, bv,
                                       q0, k0, v0);

  for (int l = 0; l < NLAYER; l++) {
    int p = l & 1;
    short* qi = p ? q1 : q0; short* ki = p ? k1 : k0; short* vi = p ? v1 : v0;
    short* qo = p ? q0 : q1; short* ko = p ? k0 : k1; short* vo = p ? v0 : v1;
    int ln = (l < NLAYER - 1) ? l + 1 : l;
    layer_kernel<<<32, 1024, 0, stream>>>(
        qi, ki, vi, bias_bf, h,
        AoT + l * 65536, bo + l * H,
        ln2_s + l * H, ln2_b + l * H,
        A1T + l * 65536, b1 + l * H,
        A2T + l * 65536, b2 + l * H,
        ln1_s + ln * H, ln1_b + ln * H,
        Aqkv + ln * 196608, bq + ln * H, bk + ln * H, bv + ln * H,
        qo, ko, vo, l == NLAYER - 1);
  }
}